// Round 1
// baseline (773.710 us; speedup 1.0000x reference)
//
#include <hip/hip_runtime.h>

// TrainableHedgehog forward as chunk-parallel linear attention.
// Shapes (hard-coded to the reference setup):
//   q,k,v: [B=2,H=16,L=2048,D=64] fp32;  Wq,Wk: [4,16,64,64] fp32; layer_idx int
//   out:   [2,16,2048,64] fp32
#define BH_N   32      // B*H
#define H_N    16
#define L_N    2048
#define D_N    64
#define F_N    64
#define FF_N   128     // 2F
#define CH_N   64      // chunk length
#define NC_N   32      // L / CH
#define EPSF   1e-12f

#define S_STRIDE (D_N*FF_N)                 // 8192 floats per (bh,chunk), layout [d][2F]
#define S_TOTAL  ((size_t)BH_N*NC_N*S_STRIDE)

__device__ __forceinline__ float wred_sum(float v){
  #pragma unroll
  for (int o=32;o>0;o>>=1) v += __shfl_xor(v,o,64);
  return v;
}
__device__ __forceinline__ float wred_max(float v){
  #pragma unroll
  for (int o=32;o>0;o>>=1) v = fmaxf(v,__shfl_xor(v,o,64));
  return v;
}
__device__ __forceinline__ float wred_min(float v){
  #pragma unroll
  for (int o=32;o>0;o>>=1) v = fminf(v,__shfl_xor(v,o,64));
  return v;
}

// Compute phi (=[softmax(o), softmax(-o)] clipped) for 16 rows of a chunk.
// One wave per 16 rows; lane = feature f in [0,64). W read from global
// (coalesced, L2-hot), x rows via wave-uniform broadcast float4 loads.
// MODE 0: lds[r][f]                         (phase-1 staging; conflict-free)
// MODE 1: lds[n][f ^ (((n>>4)&3)<<3)]       (phase-3 K tile; kills 4-way sub conflicts)
// MODE 2: lds[f][m ^ (f&31)]  (transposed)  (phase-3 Q tile; conflict-free both ways)
template<int MODE>
__device__ __forceinline__ void phi_rows16(const float* __restrict__ Wg,
                                           const float* __restrict__ Xc,
                                           int r0, int lane, float* __restrict__ lds)
{
  float o[16];
  #pragma unroll
  for (int r=0;r<16;++r) o[r]=0.f;
  #pragma unroll
  for (int d0=0; d0<4; ++d0){
    float wv[16];
    #pragma unroll
    for (int dd=0; dd<16; ++dd) wv[dd] = Wg[(d0*16+dd)*F_N + lane]; // coalesced
    #pragma unroll
    for (int r=0;r<16;++r){
      const float4* xp = reinterpret_cast<const float4*>(Xc + (size_t)(r0+r)*D_N + d0*16);
      #pragma unroll
      for (int p=0;p<4;++p){
        float4 xv = xp[p]; // wave-uniform broadcast
        o[r] += wv[p*4+0]*xv.x + wv[p*4+1]*xv.y + wv[p*4+2]*xv.z + wv[p*4+3]*xv.w;
      }
    }
  }
  #pragma unroll
  for (int r=0;r<16;++r){
    float of = o[r];
    float mP = wred_max(of);        // max(o)
    float mM = wred_min(of);        // max(-o) = -min(o)
    float eP = __expf(of - mP);
    float eM = __expf(mM - of);     // exp(-o - max(-o))
    float sP = wred_sum(eP);
    float sM = wred_sum(eM);
    float pP = fmaxf(eP/sP, EPSF);
    float pM = fmaxf(eM/sM, EPSF);
    int rr = r0 + r;
    if (MODE==0){
      lds[rr*FF_N + lane]           = pP;
      lds[rr*FF_N + F_N + lane]     = pM;
    } else if (MODE==1){
      int sw = ((rr>>4)&3)<<3;
      lds[rr*FF_N + (lane ^ sw)]        = pP;
      lds[rr*FF_N + F_N + (lane ^ sw)]  = pM;
    } else {
      lds[lane*CH_N        + (rr ^ (lane&31))] = pP;
      lds[(F_N+lane)*CH_N  + (rr ^ (lane&31))] = pM;
    }
  }
}

// ---------------- Phase 1: per-chunk S_t = phi_k^T v, z_t = sum phi_k ----------------
__global__ __launch_bounds__(256)
void hh_chunksums(const float* __restrict__ kin, const float* __restrict__ vin,
                  const float* __restrict__ Wk, const int* __restrict__ lidx,
                  float* __restrict__ S_ws, float* __restrict__ z_ws)
{
  __shared__ float phi[CH_N*FF_N]; // 32 KiB, [r][f]
  int bid = blockIdx.x;
  int bh = bid >> 5, c = bid & (NC_N-1);
  int h  = bh & (H_N-1);
  const float* Wg = Wk + (size_t)(*lidx)*(H_N*D_N*F_N) + (size_t)h*(D_N*F_N);
  const float* Xc = kin + ((size_t)bh*L_N + c*CH_N)*D_N;
  const float* Vc = vin + ((size_t)bh*L_N + c*CH_N)*D_N;
  int t = threadIdx.x, lane = t & 63, w = t >> 6;

  phi_rows16<0>(Wg, Xc, w*16, lane, phi);
  __syncthreads();

  // S[d][f] GEMM: thread (f = t&127, dg = t>>7) accumulates 32 d's
  int f = t & 127, dg = t >> 7;
  float acc[32];
  #pragma unroll
  for (int j=0;j<32;++j) acc[j]=0.f;
  float zacc = 0.f;
  for (int r=0;r<CH_N;++r){
    float pf = phi[r*FF_N + f];       // conflict-free (lanes = consecutive f)
    zacc += pf;
    const float4* vp = reinterpret_cast<const float4*>(Vc + (size_t)r*D_N + dg*32);
    #pragma unroll
    for (int p=0;p<8;++p){
      float4 vv = vp[p];              // wave-uniform broadcast, L1-hot
      acc[p*4+0] += pf*vv.x; acc[p*4+1] += pf*vv.y;
      acc[p*4+2] += pf*vv.z; acc[p*4+3] += pf*vv.w;
    }
  }
  float* Sout = S_ws + (size_t)(bh*NC_N + c)*S_STRIDE;
  #pragma unroll
  for (int j=0;j<32;++j){
    int d = dg*32 + j;
    Sout[(size_t)d*FF_N + f] = acc[j]; // coalesced across f
  }
  if (dg==0) z_ws[(size_t)(bh*NC_N + c)*FF_N + f] = zacc;
}

// ---------------- Phase 2: exclusive prefix scan over chunks ----------------
__global__ __launch_bounds__(256)
void hh_scan(float* __restrict__ S_ws, float* __restrict__ z_ws)
{
  int bid = blockIdx.x;
  int bh = bid / 33, s = bid % 33;
  int t = threadIdx.x;
  if (s < 32){
    size_t base = (size_t)bh*NC_N*S_STRIDE + (size_t)s*256 + t;
    float run = 0.f;
    float nxt = S_ws[base];
    #pragma unroll
    for (int c=0;c<NC_N;++c){
      float cur = nxt;
      if (c+1 < NC_N) nxt = S_ws[base + (size_t)(c+1)*S_STRIDE]; // 1-deep prefetch
      S_ws[base + (size_t)c*S_STRIDE] = run;
      run += cur;
    }
  } else if (t < FF_N){
    size_t base = (size_t)bh*NC_N*FF_N + t;
    float run = 0.f;
    float nxt = z_ws[base];
    #pragma unroll
    for (int c=0;c<NC_N;++c){
      float cur = nxt;
      if (c+1 < NC_N) nxt = z_ws[base + (size_t)(c+1)*FF_N];
      z_ws[base + (size_t)c*FF_N] = run;
      run += cur;
    }
  }
}

// ---------------- Phase 3: per-chunk output ----------------
__global__ __launch_bounds__(256)
void hh_output(const float* __restrict__ qin, const float* __restrict__ kin,
               const float* __restrict__ vin,
               const float* __restrict__ Wq, const float* __restrict__ Wk,
               const int* __restrict__ lidx,
               const float* __restrict__ S_ws, const float* __restrict__ z_ws,
               float* __restrict__ out)
{
  __shared__ float phiqT[FF_N*CH_N]; // 32 KiB, [f][m ^ (f&31)]
  __shared__ float phik [CH_N*FF_N]; // 32 KiB, [n][f ^ (sub<<3)]
  int bid = blockIdx.x;
  int bh = bid >> 5, c = bid & (NC_N-1);
  int h  = bh & (H_N-1);
  size_t woff = (size_t)(*lidx)*(H_N*D_N*F_N) + (size_t)h*(D_N*F_N);
  const float* Xq = qin + ((size_t)bh*L_N + c*CH_N)*D_N;
  const float* Xk = kin + ((size_t)bh*L_N + c*CH_N)*D_N;
  const float* Vc = vin + ((size_t)bh*L_N + c*CH_N)*D_N;
  const float* Sp = S_ws + (size_t)(bh*NC_N + c)*S_STRIDE; // exclusive prefix [d][2F]
  const float* zp = z_ws + (size_t)(bh*NC_N + c)*FF_N;
  int t = threadIdx.x, lane = t & 63, w = t >> 6;

  phi_rows16<2>(Wq + woff, Xq, w*16, lane, phiqT);
  phi_rows16<1>(Wk + woff, Xk, w*16, lane, phik);
  __syncthreads();

  // thread = (row mq = t>>2, sub = t&3); same-mq threads are adjacent lanes.
  int mq  = t >> 2;
  int sub = t & 3;
  int d0  = sub * 16;

  float a[16];   // A[mq][sub*16 + i]
  float acc[16]; // numerator for d = d0..d0+15
  #pragma unroll
  for (int i=0;i<16;++i){ a[i]=0.f; acc[i]=0.f; }
  float den = 0.f;

  for (int f0=0; f0<4; ++f0){            // 32-feature blocks
    float pq[32];
    #pragma unroll
    for (int ff=0; ff<32; ++ff){
      int F = f0*32 + ff;
      pq[ff] = phiqT[F*CH_N + (mq ^ (F & 31))]; // conflict-free
    }
    // denominator: phi_q . z_prefix
    const float4* zp4 = reinterpret_cast<const float4*>(zp + f0*32);
    #pragma unroll
    for (int p=0;p<8;++p){
      float4 zv = zp4[p];
      den += pq[p*4+0]*zv.x + pq[p*4+1]*zv.y + pq[p*4+2]*zv.z + pq[p*4+3]*zv.w;
    }
    // inter-chunk numerator: phi_q . S_prefix[:, d]
    #pragma unroll
    for (int j=0;j<16;++j){
      const float4* Sd = reinterpret_cast<const float4*>(Sp + (size_t)(d0+j)*FF_N + f0*32);
      float s0 = 0.f;
      #pragma unroll
      for (int p=0;p<8;++p){
        float4 sv = Sd[p];
        s0 += pq[p*4+0]*sv.x + pq[p*4+1]*sv.y + pq[p*4+2]*sv.z + pq[p*4+3]*sv.w;
      }
      acc[j] += s0;
    }
    // intra-chunk A: this thread's 16 columns n = sub*16 + i
    #pragma unroll
    for (int i=0;i<16;++i){
      int n = sub*16 + i;
      int sw = ((n>>4)&3)<<3;            // == sub<<3
      const float* pk = &phik[n*FF_N];
      float aa = 0.f;
      #pragma unroll
      for (int p=0;p<8;++p){
        float4 pkv = *reinterpret_cast<const float4*>(&pk[(f0*32 + p*4) ^ sw]);
        aa += pq[p*4+0]*pkv.x + pq[p*4+1]*pkv.y + pq[p*4+2]*pkv.z + pq[p*4+3]*pkv.w;
      }
      a[i] += aa;
    }
  }

  // exchange A across the 4 subs of this row, mask causally, accumulate PV + den
  #pragma unroll
  for (int n=0;n<64;++n){
    float an = __shfl(a[n & 15], (lane & ~3) | (n >> 4), 64);
    an = (n <= mq) ? an : 0.f;
    den += an;
    const float4* vp = reinterpret_cast<const float4*>(Vc + (size_t)n*D_N + d0);
    #pragma unroll
    for (int p=0;p<4;++p){
      float4 vv = vp[p];
      acc[p*4+0] += an*vv.x; acc[p*4+1] += an*vv.y;
      acc[p*4+2] += an*vv.z; acc[p*4+3] += an*vv.w;
    }
  }

  float inv = 1.f / (den + EPSF);
  float* Oc = out + ((size_t)bh*L_N + c*CH_N)*D_N + (size_t)mq*D_N + d0;
  #pragma unroll
  for (int p=0;p<4;++p){
    float4 ov = make_float4(acc[p*4+0]*inv, acc[p*4+1]*inv,
                            acc[p*4+2]*inv, acc[p*4+3]*inv);
    reinterpret_cast<float4*>(Oc)[p] = ov;
  }
}

extern "C" void kernel_launch(void* const* d_in, const int* in_sizes, int n_in,
                              void* d_out, int out_size, void* d_ws, size_t ws_size,
                              hipStream_t stream) {
  const float* q    = (const float*)d_in[0];
  const float* k    = (const float*)d_in[1];
  const float* v    = (const float*)d_in[2];
  const float* Wq   = (const float*)d_in[3];
  const float* Wk   = (const float*)d_in[4];
  const int*   lidx = (const int*)d_in[5];
  float* out  = (float*)d_out;
  float* S_ws = (float*)d_ws;               // 8,388,608 floats
  float* z_ws = S_ws + S_TOTAL;             // + 131,072 floats  (~34.1 MB total)

  hh_chunksums<<<BH_N*NC_N, 256, 0, stream>>>(k, v, Wk, lidx, S_ws, z_ws);
  hh_scan     <<<BH_N*33,   256, 0, stream>>>(S_ws, z_ws);
  hh_output   <<<BH_N*NC_N, 256, 0, stream>>>(q, k, v, Wq, Wk, lidx, S_ws, z_ws, out);
}

// Round 3
// 255.266 us; speedup vs baseline: 3.0310x; 3.0310x over previous
//
#include <hip/hip_runtime.h>

// TrainableHedgehog forward as chunk-parallel linear attention, MFMA edition.
// q,k,v: [2,16,2048,64] fp32; Wq,Wk: [4,16,64,64] fp32; out fp32.
// GEMMs run on v_mfma_f32_16x16x32_bf16 with hi/lo bf16 x3 splitting (~fp32 accuracy).
#define BH_N   32
#define H_N    16
#define L_N    2048
#define D_N    64
#define F_N    64
#define FF_N   128
#define CH_N   64
#define NC_N   32
#define EPSF   1e-12f

#define S_STRIDE (D_N*FF_N)                 // 8192 floats per (bh,chunk), layout [d][2F]
#define S_TOTAL  ((size_t)BH_N*NC_N*S_STRIDE)

typedef unsigned short u16;
typedef short bf16x8 __attribute__((ext_vector_type(8)));
typedef float f32x4  __attribute__((ext_vector_type(4)));

#define MFMA16(A,B,C) __builtin_amdgcn_mfma_f32_16x16x32_bf16(A,B,C,0,0,0)

__device__ __forceinline__ float wred_sum(float v){
  #pragma unroll
  for (int o=32;o>0;o>>=1) v += __shfl_xor(v,o,64);
  return v;
}
__device__ __forceinline__ float wred_max(float v){
  #pragma unroll
  for (int o=32;o>0;o>>=1) v = fmaxf(v,__shfl_xor(v,o,64));
  return v;
}
__device__ __forceinline__ float wred_min(float v){
  #pragma unroll
  for (int o=32;o>0;o>>=1) v = fminf(v,__shfl_xor(v,o,64));
  return v;
}

// fp32 -> (hi, lo) bf16 pair: x ~= hi + lo with |err| <= 2^-16 |x|
__device__ __forceinline__ void split_hl(float x, u16& h, u16& l){
  unsigned u = __float_as_uint(x);
  h = (u16)(u >> 16);
  float hf = __uint_as_float(u & 0xffff0000u);
  l = (u16)(__float_as_uint(x - hf) >> 16);
}

// Swizzled tile indices (units = elements). XOR of row low bits into the
// 16B-slot bits makes MFMA fragment reads (16 rows, same col-range) conflict-free.
__device__ __forceinline__ int ix128(int r, int c){ return (r*128 + c) ^ ((r&7)<<3); } // bf16 tile, 128 cols
__device__ __forceinline__ int ix64 (int r, int c){ return (r*64  + c) ^ ((r&7)<<3); } // bf16 tile, 64 cols
__device__ __forceinline__ int ixA  (int r, int c){ return (r*64  + c) ^ ((r&7)<<2); } // fp32 tile, 64 cols

__device__ __forceinline__ bf16x8 ldf128(const u16* t, int r, int k0){
  return *reinterpret_cast<const bf16x8*>(t + ix128(r,k0));
}
__device__ __forceinline__ bf16x8 ldf64(const u16* t, int r, int k0){
  return *reinterpret_cast<const bf16x8*>(t + ix64(r,k0));
}

__device__ __forceinline__ void cvt8(const float* __restrict__ p, bf16x8& h8, bf16x8& l8){
  f32x4 a = *reinterpret_cast<const f32x4*>(p);
  f32x4 b = *reinterpret_cast<const f32x4*>(p+4);
  float v[8] = {a[0],a[1],a[2],a[3],b[0],b[1],b[2],b[3]};
  #pragma unroll
  for (int i=0;i<8;++i){ u16 hh,ll; split_hl(v[i],hh,ll); h8[i]=(short)hh; l8[i]=(short)ll; }
}

// phi = [softmax(o), softmax(-o)] clipped, for 16 rows of a chunk; one wave,
// lane = feature f in [0,64). Stores hi/lo bf16 into swizzled LDS tiles.
// TRANS=0: tile[r][f] (128-col);  TRANS=1: tile[f][r] (64-col, transposed).
// WANT_DZ: also accumulate dz[reg] = phi_q[row].z_prefix for this lane's C-rows.
// WANT_Z : also accumulate zP/zM (per-lane column sums of phi_k).
template<int TRANS, int WANT_DZ, int WANT_Z>
__device__ __forceinline__ void phi_gen16(const float* __restrict__ Wg,
                                          const float* __restrict__ Xc,
                                          const float* __restrict__ zpref,
                                          int r0, int lane,
                                          u16* __restrict__ t_hi, u16* __restrict__ t_lo,
                                          float* __restrict__ dz, float& zPa, float& zMa)
{
  float o[16];
  #pragma unroll
  for (int r=0;r<16;++r) o[r]=0.f;
  #pragma unroll
  for (int d0=0; d0<4; ++d0){
    float wv[16];
    #pragma unroll
    for (int dd=0; dd<16; ++dd) wv[dd] = Wg[(d0*16+dd)*F_N + lane]; // coalesced
    #pragma unroll
    for (int r=0;r<16;++r){
      const float4* xp = reinterpret_cast<const float4*>(Xc + (size_t)(r0+r)*D_N + d0*16);
      #pragma unroll
      for (int p=0;p<4;++p){
        float4 xv = xp[p]; // wave-uniform broadcast
        o[r] += wv[p*4+0]*xv.x + wv[p*4+1]*xv.y + wv[p*4+2]*xv.z + wv[p*4+3]*xv.w;
      }
    }
  }
  float zq0 = 0.f, zq1 = 0.f;
  if constexpr (WANT_DZ){ zq0 = zpref[lane]; zq1 = zpref[64+lane]; }
  #pragma unroll
  for (int r=0;r<16;++r){
    float of = o[r];
    float mP = wred_max(of);
    float mM = wred_min(of);        // max(-o) = -min(o)
    float eP = __expf(of - mP);
    float eM = __expf(mM - of);
    float sP = wred_sum(eP);
    float sM = wred_sum(eM);
    float pP = fmaxf(eP/sP, EPSF);
    float pM = fmaxf(eM/sM, EPSF);
    int rr = r0 + r;
    u16 hP,lP,hM,lM; split_hl(pP,hP,lP); split_hl(pM,hM,lM);
    if constexpr (TRANS==0){
      t_hi[ix128(rr, lane)]    = hP;  t_hi[ix128(rr, 64+lane)] = hM;
      t_lo[ix128(rr, lane)]    = lP;  t_lo[ix128(rr, 64+lane)] = lM;
    } else {
      t_hi[ix64(lane, rr)]     = hP;  t_hi[ix64(64+lane, rr)]  = hM;
      t_lo[ix64(lane, rr)]     = lP;  t_lo[ix64(64+lane, rr)]  = lM;
    }
    if constexpr (WANT_DZ){
      float s = wred_sum(pP*zq0 + pM*zq1);
      if ((r>>2) == (lane>>4)) dz[r&3] = s;   // keep rows matching this lane's C-rows
    }
    if constexpr (WANT_Z){ zPa += pP; zMa += pM; }
  }
}

// ---------------- Phase 1: per-chunk S_t = phi_k^T v (MFMA), z_t = col-sums ----------------
__global__ __launch_bounds__(256)
void hh_chunksums(const float* __restrict__ kin, const float* __restrict__ vin,
                  const float* __restrict__ Wk, const int* __restrict__ lidx,
                  float* __restrict__ S_ws, float* __restrict__ z_ws)
{
  __shared__ __align__(16) char sm[51200];
  u16*  pkT_h = (u16*)sm;               // [128 f][64 r] bf16 hi  (16 KB)
  u16*  pkT_l = (u16*)(sm + 16384);     // lo                      (16 KB)
  u16*  vt_h  = (u16*)(sm + 32768);     // V^T [64 d][64 r] hi     (8 KB)
  u16*  vt_l  = (u16*)(sm + 40960);     // lo                      (8 KB)
  float* zb   = (float*)(sm + 49152);   // [4][128] partial z      (2 KB)

  int bid = blockIdx.x, bh = bid>>5, c = bid & (NC_N-1), h = bh & (H_N-1);
  const float* Wg = Wk + (size_t)(*lidx)*(H_N*D_N*F_N) + (size_t)h*(D_N*F_N);
  const float* Xk = kin + ((size_t)bh*L_N + c*CH_N)*D_N;
  const float* Vc = vin + ((size_t)bh*L_N + c*CH_N)*D_N;
  int t = threadIdx.x, lane = t&63, w = t>>6;

  // V loads early (coalesced): row vn, 16 consecutive d per thread
  int vn = t>>2, vd0 = (t&3)*16;
  float4 vreg[4];
  #pragma unroll
  for (int p=0;p<4;++p)
    vreg[p] = *reinterpret_cast<const float4*>(Vc + (size_t)vn*D_N + vd0 + p*4);

  float zP=0.f, zM=0.f; float dzd[4];
  phi_gen16<1,0,1>(Wg, Xk, nullptr, w*16, lane, pkT_h, pkT_l, dzd, zP, zM);

  // V^T staging (latency of vreg loads hidden under phi_gen)
  #pragma unroll
  for (int p=0;p<4;++p){
    float vals[4] = {vreg[p].x, vreg[p].y, vreg[p].z, vreg[p].w};
    #pragma unroll
    for (int e=0;e<4;++e){
      int d = vd0 + p*4 + e;
      u16 hh,ll; split_hl(vals[e],hh,ll);
      vt_h[ix64(d, vn)] = hh;
      vt_l[ix64(d, vn)] = ll;
    }
  }
  zb[w*128 + lane] = zP; zb[w*128 + 64 + lane] = zM;
  __syncthreads();

  if (t < FF_N)
    z_ws[(size_t)(bh*NC_N + c)*FF_N + t] = zb[t] + zb[128+t] + zb[256+t] + zb[384+t];

  // S[d][f] = sum_r V^T[d][r] * phik[r][f]; wave w owns d-tile w.
  int m0 = w*16, lrow = lane&15, k0l = (lane>>4)*8;
  f32x4 acc[8];
  #pragma unroll
  for (int ft=0; ft<8; ++ft) acc[ft] = (f32x4){0.f,0.f,0.f,0.f};
  #pragma unroll
  for (int ks=0; ks<2; ++ks){
    int r0k = ks*32 + k0l;
    bf16x8 ah = ldf64(vt_h, m0 + lrow, r0k);
    bf16x8 al = ldf64(vt_l, m0 + lrow, r0k);
    #pragma unroll
    for (int ft=0; ft<8; ++ft){
      bf16x8 bh = ldf64(pkT_h, ft*16 + lrow, r0k);
      bf16x8 bl = ldf64(pkT_l, ft*16 + lrow, r0k);
      acc[ft] = MFMA16(ah, bh, acc[ft]);
      acc[ft] = MFMA16(ah, bl, acc[ft]);
      acc[ft] = MFMA16(al, bh, acc[ft]);
    }
  }
  float* Sout = S_ws + (size_t)(bh*NC_N + c)*S_STRIDE;
  #pragma unroll
  for (int ft=0; ft<8; ++ft)
    #pragma unroll
    for (int reg=0; reg<4; ++reg){
      int d = m0 + (lane>>4)*4 + reg;
      Sout[(size_t)d*FF_N + ft*16 + lrow] = acc[ft][reg];
    }
}

// ---------------- Phase 2: exclusive prefix scan over chunks ----------------
__global__ __launch_bounds__(256)
void hh_scan(float* __restrict__ S_ws, float* __restrict__ z_ws)
{
  int bid = blockIdx.x;
  int bh = bid / 33, s = bid % 33;
  int t = threadIdx.x;
  if (s < 32){
    size_t base = (size_t)bh*NC_N*S_STRIDE + (size_t)s*256 + t;
    float run = 0.f;
    float nxt = S_ws[base];
    #pragma unroll
    for (int c=0;c<NC_N;++c){
      float cur = nxt;
      if (c+1 < NC_N) nxt = S_ws[base + (size_t)(c+1)*S_STRIDE];
      S_ws[base + (size_t)c*S_STRIDE] = run;
      run += cur;
    }
  } else if (t < FF_N){
    size_t base = (size_t)bh*NC_N*FF_N + t;
    float run = 0.f;
    float nxt = z_ws[base];
    #pragma unroll
    for (int c=0;c<NC_N;++c){
      float cur = nxt;
      if (c+1 < NC_N) nxt = z_ws[base + (size_t)(c+1)*FF_N];
      z_ws[base + (size_t)c*FF_N] = run;
      run += cur;
    }
  }
}

// ---------------- Phase 3: per-chunk output (A, numer, PV all on MFMA) ----------------
__global__ __launch_bounds__(256)
void hh_output(const float* __restrict__ qin, const float* __restrict__ kin,
               const float* __restrict__ vin,
               const float* __restrict__ Wq, const float* __restrict__ Wk,
               const int* __restrict__ lidx,
               const float* __restrict__ S_ws, const float* __restrict__ z_ws,
               float* __restrict__ out)
{
  __shared__ __align__(16) char sm[65536];
  u16*  pq_h = (u16*)sm;                // phiq [64 m][128 f] hi (16 KB)
  u16*  pq_l = (u16*)(sm + 16384);
  u16*  pk_h = (u16*)(sm + 32768);      // phik [64 n][128 f]
  u16*  pk_l = (u16*)(sm + 49152);
  float* aA  = (float*)sm;              // A [64 m][64 n] fp32 — aliases pq_h (dead by then)
  u16*  vt_h = (u16*)(sm + 16384);      // V^T [64 d][64 n]    — aliases pq_l
  u16*  vt_l = (u16*)(sm + 24576);

  int bid = blockIdx.x, bh = bid>>5, c = bid & (NC_N-1), h = bh & (H_N-1);
  size_t woff = (size_t)(*lidx)*(H_N*D_N*F_N) + (size_t)h*(D_N*F_N);
  const float* Xq = qin + ((size_t)bh*L_N + c*CH_N)*D_N;
  const float* Xk = kin + ((size_t)bh*L_N + c*CH_N)*D_N;
  const float* Vc = vin + ((size_t)bh*L_N + c*CH_N)*D_N;
  const float* Sp = S_ws + (size_t)(bh*NC_N + c)*S_STRIDE; // exclusive prefix [d][2F]
  const float* zp = z_ws + (size_t)(bh*NC_N + c)*FF_N;
  int t = threadIdx.x, lane = t&63, w = t>>6;

  // V loads early
  int vn = t>>2, vd0 = (t&3)*16;
  float4 vreg[4];
  #pragma unroll
  for (int p=0;p<4;++p)
    vreg[p] = *reinterpret_cast<const float4*>(Vc + (size_t)vn*D_N + vd0 + p*4);

  float dz[4] = {0.f,0.f,0.f,0.f};
  float zdum0=0.f, zdum1=0.f; float dzd[4];
  phi_gen16<0,1,0>(Wq + woff, Xq, zp, w*16, lane, pq_h, pq_l, dz, zdum0, zdum1);
  phi_gen16<0,0,0>(Wk + woff, Xk, nullptr, w*16, lane, pk_h, pk_l, dzd, zdum0, zdum1);
  __syncthreads();

  int m0 = w*16, lrow = lane&15, lkg = lane>>4, k0l = lkg*8;

  f32x4 accA[4], accO[4];
  #pragma unroll
  for (int i=0;i<4;++i){ accA[i]=(f32x4){0,0,0,0}; accO[i]=(f32x4){0,0,0,0}; }

  #pragma unroll
  for (int ks=0; ks<4; ++ks){
    int f0 = ks*32 + k0l;
    bf16x8 qh = ldf128(pq_h, m0 + lrow, f0);
    bf16x8 ql = ldf128(pq_l, m0 + lrow, f0);
    // intra A = phiq . phik^T (only ntiles <= w; rest stay zero)
    #pragma unroll
    for (int nt=0; nt<4; ++nt){
      if (nt <= w){
        bf16x8 kh = ldf128(pk_h, nt*16 + lrow, f0);
        bf16x8 kl = ldf128(pk_l, nt*16 + lrow, f0);
        accA[nt] = MFMA16(qh, kh, accA[nt]);
        accA[nt] = MFMA16(qh, kl, accA[nt]);
        accA[nt] = MFMA16(ql, kh, accA[nt]);
      }
    }
    // inter numer = phiq . S_prefix^T  (B-frags straight from global, hi/lo on the fly)
    #pragma unroll
    for (int dt=0; dt<4; ++dt){
      bf16x8 sh, sl;
      cvt8(Sp + (size_t)(dt*16 + lrow)*FF_N + f0, sh, sl);
      accO[dt] = MFMA16(qh, sh, accO[dt]);
      accO[dt] = MFMA16(qh, sl, accO[dt]);
      accO[dt] = MFMA16(ql, sh, accO[dt]);
    }
  }

  // causal mask own tile, row-sum for denominator
  float rs[4] = {0.f,0.f,0.f,0.f};
  #pragma unroll
  for (int nt=0; nt<4; ++nt)
    #pragma unroll
    for (int reg=0; reg<4; ++reg){
      float a = accA[nt][reg];
      if (nt > w) a = 0.f;
      if (nt == w && lrow > lkg*4 + reg) a = 0.f;  // keep n <= m
      accA[nt][reg] = a;
      rs[reg] += a;
    }
  float den[4];
  #pragma unroll
  for (int reg=0; reg<4; ++reg){
    float s = rs[reg];
    s += __shfl_xor(s,1,64); s += __shfl_xor(s,2,64);
    s += __shfl_xor(s,4,64); s += __shfl_xor(s,8,64);
    den[reg] = dz[reg] + s + EPSF;
  }

  __syncthreads();   // everyone done reading pq tiles; safe to overwrite with aA / V^T

  #pragma unroll
  for (int nt=0; nt<4; ++nt)
    #pragma unroll
    for (int reg=0; reg<4; ++reg){
      int m = m0 + lkg*4 + reg;
      aA[ixA(m, nt*16 + lrow)] = accA[nt][reg];
    }
  #pragma unroll
  for (int p=0;p<4;++p){
    float vals[4] = {vreg[p].x, vreg[p].y, vreg[p].z, vreg[p].w};
    #pragma unroll
    for (int e=0;e<4;++e){
      int d = vd0 + p*4 + e;
      u16 hh,ll; split_hl(vals[e],hh,ll);
      vt_h[ix64(d, vn)] = hh;
      vt_l[ix64(d, vn)] = ll;
    }
  }
  __syncthreads();

  // PV: accO += A . V   (waves 0,1 only need n<32 -> 1 kstep; waves 2,3 need 2)
  #pragma unroll
  for (int ks=0; ks<2; ++ks){
    if (ks <= (w>>1)){
      int n0 = ks*32 + k0l;
      int m  = m0 + lrow;
      f32x4 a0 = *reinterpret_cast<const f32x4*>(aA + ixA(m, n0));
      f32x4 a1 = *reinterpret_cast<const f32x4*>(aA + ixA(m, n0+4));
      float av[8] = {a0[0],a0[1],a0[2],a0[3],a1[0],a1[1],a1[2],a1[3]};
      bf16x8 Ah, Al;
      #pragma unroll
      for (int i=0;i<8;++i){ u16 hh,ll; split_hl(av[i],hh,ll); Ah[i]=(short)hh; Al[i]=(short)ll; }
      #pragma unroll
      for (int dt=0; dt<4; ++dt){
        bf16x8 vh = ldf64(vt_h, dt*16 + lrow, n0);
        bf16x8 vl = ldf64(vt_l, dt*16 + lrow, n0);
        accO[dt] = MFMA16(Ah, vh, accO[dt]);
        accO[dt] = MFMA16(Ah, vl, accO[dt]);
        accO[dt] = MFMA16(Al, vh, accO[dt]);
      }
    }
  }

  #pragma unroll
  for (int reg=0; reg<4; ++reg){
    float inv = 1.0f / den[reg];
    int m = m0 + lkg*4 + reg;
    float* orow = out + ((size_t)bh*L_N + c*CH_N + m)*D_N;
    #pragma unroll
    for (int dt=0; dt<4; ++dt)
      orow[dt*16 + lrow] = accO[dt][reg] * inv;
  }
}

extern "C" void kernel_launch(void* const* d_in, const int* in_sizes, int n_in,
                              void* d_out, int out_size, void* d_ws, size_t ws_size,
                              hipStream_t stream) {
  const float* q    = (const float*)d_in[0];
  const float* k    = (const float*)d_in[1];
  const float* v    = (const float*)d_in[2];
  const float* Wq   = (const float*)d_in[3];
  const float* Wk   = (const float*)d_in[4];
  const int*   lidx = (const int*)d_in[5];
  float* out  = (float*)d_out;
  float* S_ws = (float*)d_ws;               // 8,388,608 floats
  float* z_ws = S_ws + S_TOTAL;             // + 131,072 floats (~34.1 MB total)

  hh_chunksums<<<BH_N*NC_N, 256, 0, stream>>>(k, v, Wk, lidx, S_ws, z_ws);
  hh_scan     <<<BH_N*33,   256, 0, stream>>>(S_ws, z_ws);
  hh_output   <<<BH_N*NC_N, 256, 0, stream>>>(q, k, v, Wq, Wk, lidx, S_ws, z_ws, out);
}

// Round 4
// 169.504 us; speedup vs baseline: 4.5646x; 1.5060x over previous
//
#include <hip/hip_runtime.h>

// TrainableHedgehog forward as chunk-parallel linear attention, full-MFMA edition.
// q,k,v: [2,16,2048,64] fp32; Wq,Wk: [4,16,64,64] fp32; out fp32.
// All GEMM-shaped work (phi einsum, A=phiq.phik^T, numer=phiq.S^T, PV, S=V^T.phik)
// on v_mfma_f32_16x16x32_bf16 with hi/lo bf16 x3-product splitting (~fp32 accuracy).
#define BH_N   32
#define H_N    16
#define L_N    2048
#define D_N    64
#define F_N    64
#define FF_N   128
#define CH_N   64
#define NC_N   32
#define EPSF   1e-12f

#define S_STRIDE (D_N*FF_N)                 // 8192 floats per (bh,chunk), layout [d][2F]
#define S_TOTAL  ((size_t)BH_N*NC_N*S_STRIDE)
#define Z_TOTAL  ((size_t)BH_N*NC_N*FF_N)
#define WT_HEAD  (F_N*D_N)                  // 4096 elements per head
#define WT_MAT   (H_N*WT_HEAD)              // 65536 per (matrix, hi/lo half)

typedef unsigned short u16;
typedef short bf16x8 __attribute__((ext_vector_type(8)));
typedef float f32x4  __attribute__((ext_vector_type(4)));

#define MFMA16(A,B,C) __builtin_amdgcn_mfma_f32_16x16x32_bf16(A,B,C,0,0,0)

// fp32 -> (hi, lo) bf16 pair: x ~= hi + lo with |err| <= 2^-16 |x|
__device__ __forceinline__ void split_hl(float x, u16& h, u16& l){
  unsigned u = __float_as_uint(x);
  h = (u16)(u >> 16);
  float hf = __uint_as_float(u & 0xffff0000u);
  l = (u16)(__float_as_uint(x - hf) >> 16);
}

// Swizzled tile indices (units = elements). XOR of row low bits into the
// 16B-slot bits makes MFMA fragment reads (16 rows, same col-range) conflict-free.
__device__ __forceinline__ int ix128(int r, int c){ return (r*128 + c) ^ ((r&7)<<3); } // bf16, 128 cols
__device__ __forceinline__ int ix64 (int r, int c){ return (r*64  + c) ^ ((r&7)<<3); } // bf16, 64 cols
__device__ __forceinline__ int ixA  (int r, int c){ return (r*64  + c) ^ ((r&7)<<2); } // fp32, 64 cols

__device__ __forceinline__ bf16x8 ldf128(const u16* t, int r, int k0){
  return *reinterpret_cast<const bf16x8*>(t + ix128(r,k0));
}
__device__ __forceinline__ bf16x8 ldf64(const u16* t, int r, int k0){
  return *reinterpret_cast<const bf16x8*>(t + ix64(r,k0));
}

__device__ __forceinline__ void cvt8(const float* __restrict__ p, bf16x8& h8, bf16x8& l8){
  f32x4 a = *reinterpret_cast<const f32x4*>(p);
  f32x4 b = *reinterpret_cast<const f32x4*>(p+4);
  float v[8] = {a[0],a[1],a[2],a[3],b[0],b[1],b[2],b[3]};
  #pragma unroll
  for (int i=0;i<8;++i){ u16 hh,ll; split_hl(v[i],hh,ll); h8[i]=(short)hh; l8[i]=(short)ll; }
}

// ---- phi einsum on MFMA: o[m0..m0+16][0..64] in C-layout -------------------
// oacc[ft][reg] = o[m0 + (lane>>4)*4 + reg][ft*16 + (lane&15)]
__device__ __forceinline__ void o_mfma(const float* __restrict__ X,
                                       const u16* __restrict__ WTh,
                                       const u16* __restrict__ WTl,
                                       int m0, int lane, f32x4 oacc[4])
{
  int lrow = lane&15, k0l = (lane>>4)*8;
  bf16x8 xh[2], xl[2];
  #pragma unroll
  for (int ks=0; ks<2; ++ks)
    cvt8(X + (size_t)(m0+lrow)*D_N + ks*32 + k0l, xh[ks], xl[ks]);
  #pragma unroll
  for (int ft=0; ft<4; ++ft) oacc[ft] = (f32x4){0.f,0.f,0.f,0.f};
  #pragma unroll
  for (int ks=0; ks<2; ++ks){
    #pragma unroll
    for (int ft=0; ft<4; ++ft){
      const u16* bp = WTh + (ft*16+lrow)*D_N + ks*32 + k0l;
      const u16* bq = WTl + (ft*16+lrow)*D_N + ks*32 + k0l;
      bf16x8 wh = *reinterpret_cast<const bf16x8*>(bp);
      bf16x8 wl = *reinterpret_cast<const bf16x8*>(bq);
      oacc[ft] = MFMA16(xh[ks], wh, oacc[ft]);
      oacc[ft] = MFMA16(xh[ks], wl, oacc[ft]);
      oacc[ft] = MFMA16(xl[ks], wh, oacc[ft]);
    }
  }
}

// dual softmax over f (row-wise) in C-layout; 16-lane shuffle reductions.
__device__ __forceinline__ void softmax_cl(const f32x4 oacc[4], f32x4 pP[4], f32x4 pM[4])
{
  #pragma unroll
  for (int reg=0; reg<4; ++reg){
    float mP = fmaxf(fmaxf(oacc[0][reg],oacc[1][reg]), fmaxf(oacc[2][reg],oacc[3][reg]));
    float mM = fminf(fminf(oacc[0][reg],oacc[1][reg]), fminf(oacc[2][reg],oacc[3][reg]));
    #pragma unroll
    for (int o=8;o>0;o>>=1){ mP = fmaxf(mP,__shfl_xor(mP,o,64)); mM = fminf(mM,__shfl_xor(mM,o,64)); }
    float eP[4], eM[4], sP=0.f, sM=0.f;
    #pragma unroll
    for (int ft=0; ft<4; ++ft){
      eP[ft] = __expf(oacc[ft][reg]-mP);
      eM[ft] = __expf(mM-oacc[ft][reg]);
      sP += eP[ft]; sM += eM[ft];
    }
    #pragma unroll
    for (int o=8;o>0;o>>=1){ sP += __shfl_xor(sP,o,64); sM += __shfl_xor(sM,o,64); }
    float iP = 1.f/sP, iM = 1.f/sM;
    #pragma unroll
    for (int ft=0; ft<4; ++ft){
      pP[ft][reg] = fmaxf(eP[ft]*iP, EPSF);
      pM[ft][reg] = fmaxf(eM[ft]*iM, EPSF);
    }
  }
}

// store phi (C-layout regs) into swizzled LDS tile, row-major [m][128]
__device__ __forceinline__ void store_phi_rm(u16* th, u16* tl, int m0, int lane,
                                             const f32x4 pP[4], const f32x4 pM[4]){
  int lrow = lane&15, lkg = lane>>4;
  #pragma unroll
  for (int reg=0; reg<4; ++reg){
    int m = m0 + lkg*4 + reg;
    #pragma unroll
    for (int ft=0; ft<4; ++ft){
      int f = ft*16 + lrow;
      u16 hh,ll;
      split_hl(pP[ft][reg],hh,ll); th[ix128(m,f)]    = hh; tl[ix128(m,f)]    = ll;
      split_hl(pM[ft][reg],hh,ll); th[ix128(m,64+f)] = hh; tl[ix128(m,64+f)] = ll;
    }
  }
}

// store phi transposed [f][m] (for phase-1 B-frags of S = V^T . phik)
__device__ __forceinline__ void store_phi_tr(u16* th, u16* tl, int m0, int lane,
                                             const f32x4 pP[4], const f32x4 pM[4]){
  int lrow = lane&15, lkg = lane>>4;
  #pragma unroll
  for (int reg=0; reg<4; ++reg){
    int m = m0 + lkg*4 + reg;
    #pragma unroll
    for (int ft=0; ft<4; ++ft){
      int f = ft*16 + lrow;
      u16 hh,ll;
      split_hl(pP[ft][reg],hh,ll); th[ix64(f,m)]    = hh; tl[ix64(f,m)]    = ll;
      split_hl(pM[ft][reg],hh,ll); th[ix64(64+f,m)] = hh; tl[ix64(64+f,m)] = ll;
    }
  }
}

// ---------------- Phase 0: W transpose + hi/lo split (per launch, ~us) ------
__global__ __launch_bounds__(256)
void hh_wprep(const float* __restrict__ Wq, const float* __restrict__ Wk,
              const int* __restrict__ lidx, u16* __restrict__ WT)
{
  __shared__ float tile[64*65];
  int bid = blockIdx.x, which = bid & 1, h = bid >> 1;
  const float* Wsrc = (which ? Wk : Wq) + (size_t)(*lidx)*(H_N*D_N*F_N) + (size_t)h*(D_N*F_N);
  u16* dh = WT + which*(2*WT_MAT) + h*WT_HEAD;
  u16* dl = dh + WT_MAT;
  int t = threadIdx.x;
  #pragma unroll
  for (int i=0;i<16;++i){
    int idx = i*256 + t;                      // idx = d*64 + f
    tile[(idx&63)*65 + (idx>>6)] = Wsrc[idx]; // tile[f][d]
  }
  __syncthreads();
  #pragma unroll
  for (int i=0;i<16;++i){
    int idx = i*256 + t;                      // idx = f*64 + d
    float w = tile[(idx>>6)*65 + (idx&63)];
    u16 hh,ll; split_hl(w,hh,ll);
    dh[idx] = hh; dl[idx] = ll;
  }
}

// ---------------- Phase 1: per-chunk S_t = phi_k^T v (MFMA), z_t ------------
__global__ __launch_bounds__(256,3)
void hh_chunksums(const float* __restrict__ kin, const float* __restrict__ vin,
                  const u16* __restrict__ WkT,
                  float* __restrict__ S_ws, float* __restrict__ z_ws)
{
  __shared__ __align__(16) char sm[51200];
  u16*  pkT_h = (u16*)sm;               // [128 f][64 r] bf16 hi (16 KB)
  u16*  pkT_l = (u16*)(sm + 16384);
  u16*  vt_h  = (u16*)(sm + 32768);     // V^T [64 d][64 r] hi (8 KB)
  u16*  vt_l  = (u16*)(sm + 40960);
  float* zb   = (float*)(sm + 49152);   // [4][128] partial z (2 KB)

  int bid = blockIdx.x, bh = bid>>5, c = bid & (NC_N-1), h = bh & (H_N-1);
  const float* Xk = kin + ((size_t)bh*L_N + c*CH_N)*D_N;
  const float* Vc = vin + ((size_t)bh*L_N + c*CH_N)*D_N;
  const u16* Wh = WkT + h*WT_HEAD;
  const u16* Wl = Wh + WT_MAT;
  int t = threadIdx.x, lane = t&63, w = t>>6;

  // V loads early (coalesced)
  int vn = t>>2, vd0 = (t&3)*16;
  float4 vreg[4];
  #pragma unroll
  for (int p=0;p<4;++p)
    vreg[p] = *reinterpret_cast<const float4*>(Vc + (size_t)vn*D_N + vd0 + p*4);

  f32x4 oacc[4], pP[4], pM[4];
  o_mfma(Xk, Wh, Wl, w*16, lane, oacc);
  softmax_cl(oacc, pP, pM);
  store_phi_tr(pkT_h, pkT_l, w*16, lane, pP, pM);

  // z column sums (over this wave's 16 rows, then cross-lkg shuffle)
  #pragma unroll
  for (int ft=0; ft<4; ++ft){
    float sP = pP[ft][0]+pP[ft][1]+pP[ft][2]+pP[ft][3];
    float sM = pM[ft][0]+pM[ft][1]+pM[ft][2]+pM[ft][3];
    sP += __shfl_xor(sP,16,64); sP += __shfl_xor(sP,32,64);
    sM += __shfl_xor(sM,16,64); sM += __shfl_xor(sM,32,64);
    if ((lane>>4)==0){
      zb[w*128 + ft*16 + lane]      = sP;
      zb[w*128 + 64 + ft*16 + lane] = sM;
    }
  }

  // V^T staging
  #pragma unroll
  for (int p=0;p<4;++p){
    float vals[4] = {vreg[p].x, vreg[p].y, vreg[p].z, vreg[p].w};
    #pragma unroll
    for (int e=0;e<4;++e){
      int d = vd0 + p*4 + e;
      u16 hh,ll; split_hl(vals[e],hh,ll);
      vt_h[ix64(d, vn)] = hh;
      vt_l[ix64(d, vn)] = ll;
    }
  }
  __syncthreads();

  if (t < FF_N)
    z_ws[(size_t)(bh*NC_N + c)*FF_N + t] = zb[t] + zb[128+t] + zb[256+t] + zb[384+t];

  // S[d][f] = sum_r V^T[d][r] * phik[r][f]; wave w owns d-tile w.
  int m0 = w*16, lrow = lane&15, k0l = (lane>>4)*8;
  f32x4 acc[8];
  #pragma unroll
  for (int ft=0; ft<8; ++ft) acc[ft] = (f32x4){0.f,0.f,0.f,0.f};
  #pragma unroll
  for (int ks=0; ks<2; ++ks){
    int r0k = ks*32 + k0l;
    bf16x8 ah = ldf64(vt_h, m0 + lrow, r0k);
    bf16x8 al = ldf64(vt_l, m0 + lrow, r0k);
    #pragma unroll
    for (int ft=0; ft<8; ++ft){
      bf16x8 bh = ldf64(pkT_h, ft*16 + lrow, r0k);
      bf16x8 bl = ldf64(pkT_l, ft*16 + lrow, r0k);
      acc[ft] = MFMA16(ah, bh, acc[ft]);
      acc[ft] = MFMA16(ah, bl, acc[ft]);
      acc[ft] = MFMA16(al, bh, acc[ft]);
    }
  }
  float* Sout = S_ws + (size_t)(bh*NC_N + c)*S_STRIDE;
  #pragma unroll
  for (int ft=0; ft<8; ++ft)
    #pragma unroll
    for (int reg=0; reg<4; ++reg){
      int d = m0 + (lane>>4)*4 + reg;
      Sout[(size_t)d*FF_N + ft*16 + lrow] = acc[ft][reg];
    }
}

// ---------------- Phase 2: exclusive prefix scan over chunks ----------------
__global__ __launch_bounds__(256)
void hh_scan(float* __restrict__ S_ws, float* __restrict__ z_ws)
{
  int bid = blockIdx.x;
  int bh = bid / 33, s = bid % 33;
  int t = threadIdx.x;
  if (s < 32){
    size_t base = (size_t)bh*NC_N*S_STRIDE + (size_t)s*256 + t;
    float run = 0.f;
    float nxt = S_ws[base];
    #pragma unroll
    for (int c=0;c<NC_N;++c){
      float cur = nxt;
      if (c+1 < NC_N) nxt = S_ws[base + (size_t)(c+1)*S_STRIDE];
      S_ws[base + (size_t)c*S_STRIDE] = run;
      run += cur;
    }
  } else if (t < FF_N){
    size_t base = (size_t)bh*NC_N*FF_N + t;
    float run = 0.f;
    float nxt = z_ws[base];
    #pragma unroll
    for (int c=0;c<NC_N;++c){
      float cur = nxt;
      if (c+1 < NC_N) nxt = z_ws[base + (size_t)(c+1)*FF_N];
      z_ws[base + (size_t)c*FF_N] = run;
      run += cur;
    }
  }
}

// ---------------- Phase 3: per-chunk output (everything on MFMA) ------------
__global__ __launch_bounds__(256,3)
void hh_output(const float* __restrict__ qin, const float* __restrict__ kin,
               const float* __restrict__ vin,
               const u16* __restrict__ WT,   // [WqT_h|WqT_l|WkT_h|WkT_l]
               const float* __restrict__ S_ws, const float* __restrict__ z_ws,
               float* __restrict__ out)
{
  __shared__ __align__(16) char sm[32768];
  u16*  ph   = (u16*)sm;                // phi tile hi [64][128] swz (16 KB)
  u16*  pl   = (u16*)(sm + 16384);      // lo
  float* aA  = (float*)sm;              // A [64][64] fp32 — aliases ph
  u16*  vt_h = (u16*)(sm + 16384);      // V^T — aliases pl
  u16*  vt_l = (u16*)(sm + 24576);

  int bid = blockIdx.x, bh = bid>>5, c = bid & (NC_N-1), h = bh & (H_N-1);
  const float* Xq = qin + ((size_t)bh*L_N + c*CH_N)*D_N;
  const float* Xk = kin + ((size_t)bh*L_N + c*CH_N)*D_N;
  const float* Vc = vin + ((size_t)bh*L_N + c*CH_N)*D_N;
  const float* Sp = S_ws + (size_t)(bh*NC_N + c)*S_STRIDE; // exclusive prefix [d][2F]
  const float* zp = z_ws + (size_t)(bh*NC_N + c)*FF_N;
  const u16* WqTh = WT + h*WT_HEAD;
  const u16* WqTl = WqTh + WT_MAT;
  const u16* WkTh = WT + 2*WT_MAT + h*WT_HEAD;
  const u16* WkTl = WkTh + WT_MAT;
  int t = threadIdx.x, lane = t&63, w = t>>6;
  int m0 = w*16, lrow = lane&15, lkg = lane>>4, k0l = lkg*8;

  // ---- phi_q: einsum (MFMA) + softmax + dz, through own-rows LDS to A-frags
  f32x4 oacc[4], pP[4], pM[4];
  o_mfma(Xq, WqTh, WqTl, m0, lane, oacc);
  softmax_cl(oacc, pP, pM);

  float dz[4];
  {
    float zqP[4], zqM[4];
    #pragma unroll
    for (int ft=0; ft<4; ++ft){
      zqP[ft] = zp[ft*16 + lrow];
      zqM[ft] = zp[64 + ft*16 + lrow];
    }
    #pragma unroll
    for (int reg=0; reg<4; ++reg){
      float s = 0.f;
      #pragma unroll
      for (int ft=0; ft<4; ++ft)
        s += pP[ft][reg]*zqP[ft] + pM[ft][reg]*zqM[ft];
      #pragma unroll
      for (int o=8;o>0;o>>=1) s += __shfl_xor(s,o,64);
      dz[reg] = s;
    }
  }

  store_phi_rm(ph, pl, m0, lane, pP, pM);
  // Each wave reads only its own 16 rows (which only it wrote) -> no barrier.
  bf16x8 qh[4], ql[4];
  #pragma unroll
  for (int ks=0; ks<4; ++ks){
    qh[ks] = ldf128(ph, m0 + lrow, ks*32 + k0l);
    ql[ks] = ldf128(pl, m0 + lrow, ks*32 + k0l);
  }

  // ---- phi_k into the same tile (own rows again; no barrier needed yet)
  o_mfma(Xk, WkTh, WkTl, m0, lane, oacc);
  softmax_cl(oacc, pP, pM);
  store_phi_rm(ph, pl, m0, lane, pP, pM);

  // V loads (latency hidden under the MFMA section below)
  int vn = t>>2, vd0 = (t&3)*16;
  float4 vreg[4];
  #pragma unroll
  for (int p=0;p<4;++p)
    vreg[p] = *reinterpret_cast<const float4*>(Vc + (size_t)vn*D_N + vd0 + p*4);

  __syncthreads();  // all phi_k rows visible to all waves

  f32x4 accA[4], accO[4];
  #pragma unroll
  for (int i=0;i<4;++i){ accA[i]=(f32x4){0,0,0,0}; accO[i]=(f32x4){0,0,0,0}; }

  #pragma unroll
  for (int ks=0; ks<4; ++ks){
    int f0 = ks*32 + k0l;
    // intra A = phiq . phik^T (only ntiles <= w)
    #pragma unroll
    for (int nt=0; nt<4; ++nt){
      if (nt <= w){
        bf16x8 kh = ldf128(ph, nt*16 + lrow, f0);
        bf16x8 kl = ldf128(pl, nt*16 + lrow, f0);
        accA[nt] = MFMA16(qh[ks], kh, accA[nt]);
        accA[nt] = MFMA16(qh[ks], kl, accA[nt]);
        accA[nt] = MFMA16(ql[ks], kh, accA[nt]);
      }
    }
    // inter numer = phiq . S_prefix^T (B-frags from global, hi/lo on the fly)
    #pragma unroll
    for (int dt=0; dt<4; ++dt){
      bf16x8 sh, sl;
      cvt8(Sp + (size_t)(dt*16 + lrow)*FF_N + f0, sh, sl);
      accO[dt] = MFMA16(qh[ks], sh, accO[dt]);
      accO[dt] = MFMA16(qh[ks], sl, accO[dt]);
      accO[dt] = MFMA16(ql[ks], sh, accO[dt]);
    }
  }

  // causal mask own tile, row-sum for denominator
  float rs[4] = {0.f,0.f,0.f,0.f};
  #pragma unroll
  for (int nt=0; nt<4; ++nt)
    #pragma unroll
    for (int reg=0; reg<4; ++reg){
      float a = accA[nt][reg];
      if (nt > w) a = 0.f;
      if (nt == w && lrow > lkg*4 + reg) a = 0.f;  // keep n <= m
      accA[nt][reg] = a;
      rs[reg] += a;
    }
  float den[4];
  #pragma unroll
  for (int reg=0; reg<4; ++reg){
    float s = rs[reg];
    s += __shfl_xor(s,1,64); s += __shfl_xor(s,2,64);
    s += __shfl_xor(s,4,64); s += __shfl_xor(s,8,64);
    den[reg] = dz[reg] + s + EPSF;
  }

  __syncthreads();   // all waves done reading phik tile; safe to alias

  #pragma unroll
  for (int nt=0; nt<4; ++nt)
    #pragma unroll
    for (int reg=0; reg<4; ++reg){
      int m = m0 + lkg*4 + reg;
      aA[ixA(m, nt*16 + lrow)] = accA[nt][reg];
    }
  #pragma unroll
  for (int p=0;p<4;++p){
    float vals[4] = {vreg[p].x, vreg[p].y, vreg[p].z, vreg[p].w};
    #pragma unroll
    for (int e=0;e<4;++e){
      int d = vd0 + p*4 + e;
      u16 hh,ll; split_hl(vals[e],hh,ll);
      vt_h[ix64(d, vn)] = hh;
      vt_l[ix64(d, vn)] = ll;
    }
  }
  __syncthreads();

  // PV: accO += A . V   (waves 0,1 need 1 kstep; waves 2,3 need 2)
  #pragma unroll
  for (int ks=0; ks<2; ++ks){
    if (ks <= (w>>1)){
      int n0 = ks*32 + k0l;
      int m  = m0 + lrow;
      f32x4 a0 = *reinterpret_cast<const f32x4*>(aA + ixA(m, n0));
      f32x4 a1 = *reinterpret_cast<const f32x4*>(aA + ixA(m, n0+4));
      float av[8] = {a0[0],a0[1],a0[2],a0[3],a1[0],a1[1],a1[2],a1[3]};
      bf16x8 Ah, Al;
      #pragma unroll
      for (int i=0;i<8;++i){ u16 hh,ll; split_hl(av[i],hh,ll); Ah[i]=(short)hh; Al[i]=(short)ll; }
      #pragma unroll
      for (int dt=0; dt<4; ++dt){
        bf16x8 vh = ldf64(vt_h, dt*16 + lrow, n0);
        bf16x8 vl = ldf64(vt_l, dt*16 + lrow, n0);
        accO[dt] = MFMA16(Ah, vh, accO[dt]);
        accO[dt] = MFMA16(Ah, vl, accO[dt]);
        accO[dt] = MFMA16(Al, vh, accO[dt]);
      }
    }
  }

  #pragma unroll
  for (int reg=0; reg<4; ++reg){
    float inv = 1.0f / den[reg];
    int m = m0 + lkg*4 + reg;
    float* orow = out + ((size_t)bh*L_N + c*CH_N + m)*D_N;
    #pragma unroll
    for (int dt=0; dt<4; ++dt)
      orow[dt*16 + lrow] = accO[dt][reg] * inv;
  }
}

extern "C" void kernel_launch(void* const* d_in, const int* in_sizes, int n_in,
                              void* d_out, int out_size, void* d_ws, size_t ws_size,
                              hipStream_t stream) {
  const float* q    = (const float*)d_in[0];
  const float* k    = (const float*)d_in[1];
  const float* v    = (const float*)d_in[2];
  const float* Wq   = (const float*)d_in[3];
  const float* Wk   = (const float*)d_in[4];
  const int*   lidx = (const int*)d_in[5];
  float* out  = (float*)d_out;
  float* S_ws = (float*)d_ws;                         // 33.55 MB
  float* z_ws = S_ws + S_TOTAL;                       // 0.52 MB
  u16*   WT   = (u16*)((char*)d_ws + (S_TOTAL + Z_TOTAL)*sizeof(float)); // 0.5 MB

  hh_wprep    <<<2*H_N,     256, 0, stream>>>(Wq, Wk, lidx, WT);
  hh_chunksums<<<BH_N*NC_N, 256, 0, stream>>>(k, v, WT + 2*WT_MAT, S_ws, z_ws);
  hh_scan     <<<BH_N*33,   256, 0, stream>>>(S_ws, z_ws);
  hh_output   <<<BH_N*NC_N, 256, 0, stream>>>(q, k, v, WT, S_ws, z_ws, out);
}